// Round 10
// baseline (208.890 us; speedup 1.0000x reference)
//
#include <hip/hip_runtime.h>

typedef unsigned int uint;
typedef unsigned short ushort;
typedef __attribute__((ext_vector_type(8))) short bf16x8;
typedef __attribute__((ext_vector_type(4))) float f32x4;

namespace {
constexpr int kS = 2048;
constexpr int kD = 512;
constexpr int kH = 8;
constexpr int kNT = 8192;  // B*S
constexpr int kBand = 16;
}  // namespace

static __device__ __forceinline__ ushort f2bf(float f) {
  uint u = __builtin_bit_cast(uint, f);
  u = (u + 0x7fffu + ((u >> 16) & 1u)) >> 16;  // RNE
  return (ushort)u;
}

// ---------------------------------------------------------------------------
// Weight prep: WT[z][n][k] = bf16(W[z][k][n]). grid 256, block 256.
// ---------------------------------------------------------------------------
__global__ __launch_bounds__(256) void prep_w_kernel(
    const float* __restrict__ wq, const float* __restrict__ wk,
    const float* __restrict__ wv, const float* __restrict__ wo,
    ushort* __restrict__ WT) {
  __shared__ float Ws[64][65];
  const int w = blockIdx.x;  // 0..255
  const int tid = threadIdx.x;
  const int z = w >> 6;
  const float* W = z == 0 ? wq : (z == 1 ? wk : (z == 2 ? wv : wo));
  ushort* T = WT + (size_t)z * kD * kD;
  const int kt = ((w >> 3) & 7) * 64, nt = (w & 7) * 64;
  const int r = tid >> 2, c0 = (tid & 3) * 16;
#pragma unroll
  for (int i = 0; i < 4; ++i) {
    const float4 x =
        *(const float4*)(W + (size_t)(kt + r) * kD + nt + c0 + i * 4);
    Ws[r][c0 + i * 4 + 0] = x.x;
    Ws[r][c0 + i * 4 + 1] = x.y;
    Ws[r][c0 + i * 4 + 2] = x.z;
    Ws[r][c0 + i * 4 + 3] = x.w;
  }
  __syncthreads();
  const int n = tid >> 2, k0 = (tid & 3) * 16;
  alignas(16) ushort tmp[16];
#pragma unroll
  for (int i = 0; i < 16; ++i) tmp[i] = f2bf(Ws[k0 + i][n]);
  ushort* dst = T + (size_t)(nt + n) * kD + kt + k0;
  *(uint4*)(dst + 0) = *(const uint4*)&tmp[0];
  *(uint4*)(dst + 8) = *(const uint4*)&tmp[8];
}

// ---------------------------------------------------------------------------
// Barrier-free direct-fragment 128x128 GEMM. No LDS staging in the K-loop:
// each lane loads its MFMA A/B fragments (8 contiguous bf16 / 8 fp32 + cvt)
// straight from global. Wave redundancy (x2 A rows, x2 B cols per block) is
// absorbed by the XCD-swizzled L2. LDS used only for the epilogue transpose
// (wave-private region, no __syncthreads anywhere).
// mode = mode_arg + blockIdx.z:
//   0: q @ WTq + bq -> Qp (bf16)   1: k @ WTk + bk -> Kp (bf16)
//   2: v @ WTv + bv -> VT (bf16 [bh*64+d][2048])
//   3: Ob @ WTo + bo -> out (fp32)
// ---------------------------------------------------------------------------
template <bool F32A>
__global__ __launch_bounds__(256) void gemm_kernel(
    const float* __restrict__ qf, const float* __restrict__ kf,
    const float* __restrict__ vf, const ushort* __restrict__ obp,
    const ushort* __restrict__ WT, const float* __restrict__ bq,
    const float* __restrict__ bk, const float* __restrict__ bv,
    const float* __restrict__ bo, ushort* __restrict__ Qp,
    ushort* __restrict__ Kp, ushort* __restrict__ VT,
    float* __restrict__ outp, int mode_arg) {
  const int mode = mode_arg + blockIdx.z;
  const float* Af = nullptr;
  const ushort* Ab = nullptr;
  const float* bias;
  switch (mode) {
    case 0: Af = qf; bias = bq; break;
    case 1: Af = kf; bias = bk; break;
    case 2: Af = vf; bias = bv; break;
    default: Ab = obp; bias = bo; break;
  }
  const ushort* BT = WT + (size_t)mode * kD * kD;

  __shared__ alignas(16) ushort smem[18432];  // 4 waves x 64 x 72 (epilogue)

  const int tid = threadIdx.x;
  const int wave = tid >> 6, lane = tid & 63, l15 = lane & 15, qd = lane >> 4;
  const int wm = (wave >> 1) * 64, wn = (wave & 1) * 64;
  // XCD-aware swizzle: x%8 = XCD; 4 col-blocks of a row-block share an XCD.
  const int lin = blockIdx.x;
  const int xcd = lin & 7, j = lin >> 3;
  const int rblk = xcd + 8 * (j >> 2), cblk = j & 3;
  const int row0 = rblk * 128, col0 = cblk * 128;

  const float* aF[4];
  const ushort* aB[4];
  const ushort* bP[4];
#pragma unroll
  for (int mi = 0; mi < 4; ++mi) {
    const int row = row0 + wm + mi * 16 + l15;
    if constexpr (F32A)
      aF[mi] = Af + (size_t)row * kD + qd * 8;
    else
      aB[mi] = Ab + (size_t)row * kD + qd * 8;
  }
#pragma unroll
  for (int ni = 0; ni < 4; ++ni)
    bP[ni] = BT + (size_t)(col0 + wn + ni * 16 + l15) * kD + qd * 8;

  f32x4 acc[4][4];
#pragma unroll
  for (int mi = 0; mi < 4; ++mi)
#pragma unroll
    for (int ni = 0; ni < 4; ++ni) acc[mi][ni] = (f32x4)(0.f);

#pragma unroll 2
  for (int k0 = 0; k0 < kD; k0 += 32) {
    bf16x8 af[4], br[4];
#pragma unroll
    for (int ni = 0; ni < 4; ++ni) br[ni] = *(const bf16x8*)(bP[ni] + k0);
    if constexpr (F32A) {
#pragma unroll
      for (int mi = 0; mi < 4; ++mi) {
        const float4 x0 = *(const float4*)(aF[mi] + k0);
        const float4 x1 = *(const float4*)(aF[mi] + k0 + 4);
        bf16x8 t;
        t[0] = (short)f2bf(x0.x);
        t[1] = (short)f2bf(x0.y);
        t[2] = (short)f2bf(x0.z);
        t[3] = (short)f2bf(x0.w);
        t[4] = (short)f2bf(x1.x);
        t[5] = (short)f2bf(x1.y);
        t[6] = (short)f2bf(x1.z);
        t[7] = (short)f2bf(x1.w);
        af[mi] = t;
      }
    } else {
#pragma unroll
      for (int mi = 0; mi < 4; ++mi) af[mi] = *(const bf16x8*)(aB[mi] + k0);
    }
#pragma unroll
    for (int mi = 0; mi < 4; ++mi)
#pragma unroll
      for (int ni = 0; ni < 4; ++ni)
        acc[mi][ni] = __builtin_amdgcn_mfma_f32_16x16x32_bf16(
            af[mi], br[ni], acc[mi][ni], 0, 0, 0);
  }

  float bcol[4];
#pragma unroll
  for (int ni = 0; ni < 4; ++ni) bcol[ni] = bias[col0 + wn + ni * 16 + l15];

  if (mode == 3) {  // fp32 direct stores
#pragma unroll
    for (int mi = 0; mi < 4; ++mi)
#pragma unroll
      for (int ni = 0; ni < 4; ++ni) {
        const int n_g = col0 + wn + ni * 16 + l15;
#pragma unroll
        for (int r = 0; r < 4; ++r) {
          const int token = row0 + wm + mi * 16 + qd * 4 + r;
          outp[(size_t)token * kD + n_g] = acc[mi][ni][r] + bcol[ni];
        }
      }
    return;
  }

  // bf16 outputs: per-wave 64x64 transpose in a wave-private LDS region
  // (stride 72 ushorts), then 8 x dwordx4 stores per lane. No block sync.
  ushort* T = &smem[wave * 4608];
  if (mode <= 1) {  // [token_local][d_local]
#pragma unroll
    for (int mi = 0; mi < 4; ++mi)
#pragma unroll
      for (int ni = 0; ni < 4; ++ni)
#pragma unroll
        for (int r = 0; r < 4; ++r)
          T[(mi * 16 + qd * 4 + r) * 72 + ni * 16 + l15] =
              f2bf(acc[mi][ni][r] + bcol[ni]);
  } else {  // mode 2: [d_local][token_local]
#pragma unroll
    for (int mi = 0; mi < 4; ++mi)
#pragma unroll
      for (int ni = 0; ni < 4; ++ni)
#pragma unroll
        for (int r = 0; r < 4; ++r)
          T[(ni * 16 + l15) * 72 + mi * 16 + qd * 4 + r] =
              f2bf(acc[mi][ni][r] + bcol[ni]);
  }
  asm volatile("s_waitcnt lgkmcnt(0)" ::: "memory");  // wave-local visibility

  const ushort* Trow = &smem[wave * 4608 + lane * 72];
  if (mode <= 1) {
    ushort* C = (mode == 0) ? Qp : Kp;
    ushort* dst = C + (size_t)(row0 + wm + lane) * kD + col0 + wn;
#pragma unroll
    for (int c = 0; c < 8; ++c)
      *(uint4*)(dst + c * 8) = *(const uint4*)(Trow + c * 8);
  } else {
    const int n_g = col0 + wn + lane;
    const int h = n_g >> 6, d = n_g & 63;
    const int t0 = row0 + wm;
    const int b = t0 >> 11, ss = t0 & (kS - 1);
    ushort* dst = VT + ((size_t)(b * kH + h) * 64 + d) * kS + ss;
#pragma unroll
    for (int c = 0; c < 8; ++c)
      *(uint4*)(dst + c * 8) = *(const uint4*)(Trow + c * 8);
  }
}

// ---------------------------------------------------------------------------
// MFMA banded attention. One wave per 64-query tile per (b,h). grid (32,32).
// ---------------------------------------------------------------------------
__global__ __launch_bounds__(64, 1) void attn_kernel(
    const ushort* __restrict__ Qp, const ushort* __restrict__ Kp,
    const ushort* __restrict__ VT, ushort* __restrict__ Ob) {
  __shared__ alignas(16) ushort Pl[64 * 104];

  const int lane = threadIdx.x, l15 = lane & 15, qd = lane >> 4;
  const int bh = blockIdx.y, b = bh >> 3, h = bh & 7;
  const int q0 = blockIdx.x * 64;
  const int colA = h * 64;

  bf16x8 qf[4][2], kf[6][2];
#pragma unroll
  for (int mi = 0; mi < 4; ++mi) {
    const size_t base =
        ((size_t)b * kS + q0 + mi * 16 + l15) * kD + colA + qd * 8;
#pragma unroll
    for (int kc = 0; kc < 2; ++kc)
      qf[mi][kc] = *(const bf16x8*)&Qp[base + kc * 32];
  }
#pragma unroll
  for (int ni = 0; ni < 6; ++ni) {
    int key = q0 - kBand + ni * 16 + l15;
    key = key < 0 ? 0 : (key > kS - 1 ? kS - 1 : key);  // clamp; masked below
    const size_t base = ((size_t)b * kS + key) * kD + colA + qd * 8;
#pragma unroll
    for (int kc = 0; kc < 2; ++kc)
      kf[ni][kc] = *(const bf16x8*)&Kp[base + kc * 32];
  }

  f32x4 S[4][6];
#pragma unroll
  for (int mi = 0; mi < 4; ++mi)
#pragma unroll
    for (int ni = 0; ni < 6; ++ni) S[mi][ni] = (f32x4)(0.f);
#pragma unroll
  for (int mi = 0; mi < 4; ++mi)
#pragma unroll
    for (int ni = 0; ni < 6; ++ni)
#pragma unroll
      for (int kc = 0; kc < 2; ++kc)
        S[mi][ni] = __builtin_amdgcn_mfma_f32_16x16x32_bf16(
            qf[mi][kc], kf[ni][kc], S[mi][ni], 0, 0, 0);

#pragma unroll
  for (int mi = 0; mi < 4; ++mi)
#pragma unroll
    for (int ni = 0; ni < 6; ++ni)
#pragma unroll
      for (int r = 0; r < 4; ++r) {
        const int q_local = mi * 16 + qd * 4 + r;
        const int key_local = ni * 16 + l15;
        const int key = q0 - kBand + key_local;
        const int dlt = key_local - q_local;
        const bool ok = (dlt >= 0) && (dlt <= 32) && (key >= 0) && (key < kS);
        S[mi][ni][r] = ok ? S[mi][ni][r] * 0.125f : -3.0e38f;
      }

  float inv[4][4];
#pragma unroll
  for (int mi = 0; mi < 4; ++mi)
#pragma unroll
    for (int r = 0; r < 4; ++r) {
      float m = S[mi][0][r];
#pragma unroll
      for (int ni = 1; ni < 6; ++ni) m = fmaxf(m, S[mi][ni][r]);
      m = fmaxf(m, __shfl_xor(m, 1));
      m = fmaxf(m, __shfl_xor(m, 2));
      m = fmaxf(m, __shfl_xor(m, 4));
      m = fmaxf(m, __shfl_xor(m, 8));
      float s = 0.f;
#pragma unroll
      for (int ni = 0; ni < 6; ++ni) {
        const float e = __expf(S[mi][ni][r] - m);
        S[mi][ni][r] = e;
        s += e;
      }
      s += __shfl_xor(s, 1);
      s += __shfl_xor(s, 2);
      s += __shfl_xor(s, 4);
      s += __shfl_xor(s, 8);
      inv[mi][r] = 1.f / s;
    }

#pragma unroll
  for (int mi = 0; mi < 4; ++mi)
#pragma unroll
    for (int ni = 0; ni < 6; ++ni)
#pragma unroll
      for (int r = 0; r < 4; ++r)
        Pl[(mi * 16 + qd * 4 + r) * 104 + ni * 16 + l15] = f2bf(S[mi][ni][r]);
  __syncthreads();

  f32x4 O[4][4];
#pragma unroll
  for (int mi = 0; mi < 4; ++mi)
#pragma unroll
    for (int nt = 0; nt < 4; ++nt) O[mi][nt] = (f32x4)(0.f);

#pragma unroll
  for (int kc = 0; kc < 3; ++kc) {
    bf16x8 pf[4], vfr[4];
#pragma unroll
    for (int mi = 0; mi < 4; ++mi)
      pf[mi] = *(const bf16x8*)&Pl[(mi * 16 + l15) * 104 + kc * 32 + qd * 8];
    int kb0 = q0 - kBand + kc * 32 + qd * 8;
    kb0 = kb0 < 0 ? 0 : (kb0 > kS - 8 ? kS - 8 : kb0);
#pragma unroll
    for (int nt = 0; nt < 4; ++nt)
      vfr[nt] =
          *(const bf16x8*)&VT[((size_t)bh * 64 + nt * 16 + l15) * kS + kb0];
#pragma unroll
    for (int mi = 0; mi < 4; ++mi)
#pragma unroll
      for (int nt = 0; nt < 4; ++nt)
        O[mi][nt] = __builtin_amdgcn_mfma_f32_16x16x32_bf16(pf[mi], vfr[nt],
                                                            O[mi][nt], 0, 0, 0);
  }

#pragma unroll
  for (int mi = 0; mi < 4; ++mi)
#pragma unroll
    for (int nt = 0; nt < 4; ++nt)
#pragma unroll
      for (int r = 0; r < 4; ++r)
        Pl[(mi * 16 + qd * 4 + r) * 72 + nt * 16 + l15] =
            f2bf(O[mi][nt][r] * inv[mi][r]);
  asm volatile("s_waitcnt lgkmcnt(0)" ::: "memory");

  ushort* dst = Ob + ((size_t)b * kS + q0 + lane) * kD + colA;
  const ushort* Trow = &Pl[lane * 72];
#pragma unroll
  for (int c = 0; c < 8; ++c)
    *(uint4*)(dst + c * 8) = *(const uint4*)(Trow + c * 8);
}

extern "C" void kernel_launch(void* const* d_in, const int* in_sizes, int n_in,
                              void* d_out, int out_size, void* d_ws,
                              size_t ws_size, hipStream_t stream) {
  const float* q = (const float*)d_in[0];
  const float* k = (const float*)d_in[1];
  const float* v = (const float*)d_in[2];
  const float* wq = (const float*)d_in[3];
  const float* bq = (const float*)d_in[4];
  const float* wk = (const float*)d_in[5];
  const float* bk = (const float*)d_in[6];
  const float* wv = (const float*)d_in[7];
  const float* bv = (const float*)d_in[8];
  const float* wo = (const float*)d_in[9];
  const float* bo = (const float*)d_in[10];
  float* out = (float*)d_out;

  // ws (~34 MB): Qp | Kp | VT | Ob | WT
  const size_t n1 = (size_t)kNT * kD;  // 8 MB each (bf16)
  ushort* Qp = (ushort*)d_ws;
  ushort* Kp = Qp + n1;
  ushort* VT = Kp + n1;
  ushort* Ob = VT + n1;
  ushort* WT = Ob + n1;

  prep_w_kernel<<<dim3(256), 256, 0, stream>>>(wq, wk, wv, wo, WT);
  gemm_kernel<true><<<dim3(256, 1, 3), 256, 0, stream>>>(  // modes 0,1,2
      q, k, v, Ob, WT, bq, bk, bv, bo, Qp, Kp, VT, out, 0);
  attn_kernel<<<dim3(kS / 64, 32), 64, 0, stream>>>(Qp, Kp, VT, Ob);
  gemm_kernel<false><<<dim3(256, 1, 1), 256, 0, stream>>>(  // mode 3
      q, k, v, Ob, WT, bq, bk, bv, bo, Qp, Kp, VT, out, 3);
}

// Round 11
// 161.083 us; speedup vs baseline: 1.2968x; 1.2968x over previous
//
#include <hip/hip_runtime.h>

typedef unsigned int uint;
typedef unsigned short ushort;
typedef __attribute__((ext_vector_type(8))) short bf16x8;
typedef __attribute__((ext_vector_type(4))) float f32x4;

namespace {
constexpr int kS = 2048;
constexpr int kD = 512;
constexpr int kH = 8;
constexpr int kNT = 8192;  // B*S
constexpr int kBand = 16;
}  // namespace

static __device__ __forceinline__ ushort f2bf(float f) {
  uint u = __builtin_bit_cast(uint, f);
  u = (u + 0x7fffu + ((u >> 16) & 1u)) >> 16;  // RNE
  return (ushort)u;
}

// global -> LDS direct DMA, 16B/lane. LDS dest = wave-uniform base + lane*16.
#define GLD16(gp, lp)                                                   \
  __builtin_amdgcn_global_load_lds(                                     \
      (const __attribute__((address_space(1))) uint*)(gp),              \
      (__attribute__((address_space(3))) uint*)(lp), 16, 0, 0)

// ---------------------------------------------------------------------------
// Weight prep: WT[z][n][k] = bf16(W[z][k][n]). grid 256, block 256.
// ---------------------------------------------------------------------------
__global__ __launch_bounds__(256) void prep_w_kernel(
    const float* __restrict__ wq, const float* __restrict__ wk,
    const float* __restrict__ wv, const float* __restrict__ wo,
    ushort* __restrict__ WT) {
  __shared__ float Ws[64][65];
  const int w = blockIdx.x;  // 0..255
  const int tid = threadIdx.x;
  const int z = w >> 6;
  const float* W = z == 0 ? wq : (z == 1 ? wk : (z == 2 ? wv : wo));
  ushort* T = WT + (size_t)z * kD * kD;
  const int kt = ((w >> 3) & 7) * 64, nt = (w & 7) * 64;
  const int r = tid >> 2, c0 = (tid & 3) * 16;
#pragma unroll
  for (int i = 0; i < 4; ++i) {
    const float4 x =
        *(const float4*)(W + (size_t)(kt + r) * kD + nt + c0 + i * 4);
    Ws[r][c0 + i * 4 + 0] = x.x;
    Ws[r][c0 + i * 4 + 1] = x.y;
    Ws[r][c0 + i * 4 + 2] = x.z;
    Ws[r][c0 + i * 4 + 3] = x.w;
  }
  __syncthreads();
  const int n = tid >> 2, k0 = (tid & 3) * 16;
  alignas(16) ushort tmp[16];
#pragma unroll
  for (int i = 0; i < 16; ++i) tmp[i] = f2bf(Ws[k0 + i][n]);
  ushort* dst = T + (size_t)(nt + n) * kD + kt + k0;
  *(uint4*)(dst + 0) = *(const uint4*)&tmp[0];
  *(uint4*)(dst + 8) = *(const uint4*)&tmp[8];
}

// ---------------------------------------------------------------------------
// TM x 128 BK=32 bf16 MFMA GEMM, 3-stage pipeline, raw s_barrier + vmcnt.
// F32A=true (TM=128): A read fp32 -> regs (double-buffered), cvt -> ds_write.
//   ORDER-CRITICAL (R9 bug): per iter, CVT(it+1) is issued FIRST, then
//   afp(it+2) loads, then ISSUE_B(it+2). afp(s) always issued before B(s),
//   so the CVT's implicit wait (vmcnt counts younger loads) drains only afp,
//   never the B pipeline. Barrier wait vmcnt(6) = afp(it+1)[4]+B(it+1)[2].
// F32A=false: A staged via DMA like B; per-stage loads = TM/64 + 2.
// XCD-aware swizzle: 4 col-blocks of a row-block share an XCD (x%8).
// mode = mode_arg + blockIdx.z:
//   0: q @ WTq + bq -> Qp (bf16)   1: k @ WTk + bk -> Kp (bf16)
//   2: v @ WTv + bv -> VT (bf16 [bh*64+d][2048])
//   3: Ob @ WTo + bo -> out (fp32)
// ---------------------------------------------------------------------------
template <int TM, bool F32A>
__global__ __launch_bounds__(256) void gemm_kernel(
    const float* __restrict__ qf, const float* __restrict__ kf,
    const float* __restrict__ vf, const ushort* __restrict__ obp,
    const ushort* __restrict__ WT, const float* __restrict__ bq,
    const float* __restrict__ bk, const float* __restrict__ bv,
    const float* __restrict__ bo, ushort* __restrict__ Qp,
    ushort* __restrict__ Kp, ushort* __restrict__ VT,
    float* __restrict__ outp, int mode_arg) {
  const int mode = mode_arg + blockIdx.z;
  const float* Af = nullptr;
  const ushort* Ab = nullptr;
  const float* bias;
  switch (mode) {
    case 0: Af = qf; bias = bq; break;
    case 1: Af = kf; bias = bk; break;
    case 2: Af = vf; bias = bv; break;
    default: Ab = obp; bias = bo; break;
  }
  const ushort* BT = WT + (size_t)mode * kD * kD;

  constexpr int A_STAGE = TM * 32;
  constexpr int B_BASE = 3 * A_STAGE;
  constexpr int NI = (TM == 128) ? 4 : 2;
  constexpr int AI = TM / 64;
  __shared__ alignas(16) ushort smem[B_BASE + 12288];

  const int tid = threadIdx.x;
  const int wave = tid >> 6, lane = tid & 63, l15 = lane & 15, qd = lane >> 4;
  const int wm = (TM == 128) ? (wave >> 1) * 64 : 0;
  const int wn = (TM == 128) ? (wave & 1) * 64 : wave * 32;
  const int lin = blockIdx.x;
  const int xcd = lin & 7, j = lin >> 3;
  const int rblk = xcd + 8 * (j >> 2), cblk = j & 3;
  const int row0 = rblk * TM, col0 = cblk * 128;
  const int sw = (l15 & 3) ^ (l15 >> 2);

  // B DMA mapping (chunk c of row r holds global chunk c^s(r))
  const ushort* pB[2];
  uint ldsB[2];
#pragma unroll
  for (int i = 0; i < 2; ++i) {
    const int linear = i * 256 + tid;
    const int r = linear >> 2, c = linear & 3;
    const int g = c ^ ((r & 3) ^ ((r >> 2) & 3));
    pB[i] = BT + (size_t)(col0 + r) * kD + g * 8;
    ldsB[i] = (uint)B_BASE + (uint)(i * 256 + wave * 64) * 8;
  }
#define ISSUE_B(kk, st)                                \
  {                                                    \
    GLD16(pB[0] + (kk), &smem[ldsB[0] + (st) * 4096]); \
    GLD16(pB[1] + (kk), &smem[ldsB[1] + (st) * 4096]); \
  }

  const ushort* pA[AI];
  uint ldsAd[AI];
  const float* pAf[4];
  uint ldsAw[4];
  float4 afp[2][4];
  if constexpr (!F32A) {
#pragma unroll
    for (int i = 0; i < AI; ++i) {
      const int linear = i * 256 + tid;
      const int r = linear >> 2, c = linear & 3;
      const int g = c ^ ((r & 3) ^ ((r >> 2) & 3));
      pA[i] = Ab + (size_t)(row0 + r) * kD + g * 8;
      ldsAd[i] = (uint)(i * 256 + wave * 64) * 8;
    }
  } else {
#pragma unroll
    for (int i = 0; i < 4; ++i) {
      const int idx = i * 256 + tid;
      const int r = idx >> 3, c = idx & 7;
      pAf[i] = Af + (size_t)(row0 + r) * kD + c * 4;
      ldsAw[i] =
          (uint)(r * 32 + (((c >> 1) ^ ((r & 3) ^ ((r >> 2) & 3))) * 8) +
                 (c & 1) * 4);
    }
  }
#define ISSUE_A_DMA(kk, st)                                    \
  {                                                            \
    _Pragma("unroll") for (int i = 0; i < AI; ++i)             \
        GLD16(pA[i] + (kk), &smem[ldsAd[i] + (st) * A_STAGE]); \
  }
#define LOAD_AFP(kk, buf)                                         \
  {                                                               \
    _Pragma("unroll") for (int i = 0; i < 4; ++i) afp[buf][i] =   \
        *(const float4*)(pAf[i] + (kk));                          \
  }
#define CVT_WRITE_A(st, buf)                                          \
  {                                                                   \
    _Pragma("unroll") for (int i = 0; i < 4; ++i) {                   \
      const float4 x = afp[buf][i];                                   \
      const uint lo = (uint)f2bf(x.x) | ((uint)f2bf(x.y) << 16);      \
      const uint hi = (uint)f2bf(x.z) | ((uint)f2bf(x.w) << 16);      \
      *(uint2*)&smem[ldsAw[i] + (st) * A_STAGE] = make_uint2(lo, hi); \
    }                                                                 \
  }

  f32x4 acc[4][NI];
#pragma unroll
  for (int mi = 0; mi < 4; ++mi)
#pragma unroll
    for (int ni = 0; ni < NI; ++ni) acc[mi][ni] = (f32x4)(0.f);

  // prologue — afp(s) always issued before B(s)
  if constexpr (F32A) {
    LOAD_AFP(0, 0);
    ISSUE_B(0, 0);
    LOAD_AFP(32, 1);
    ISSUE_B(32, 1);
    CVT_WRITE_A(0, 0);  // implicit wait drains afp0 only (B0/afp1/B1 younger)
  } else {
    ISSUE_A_DMA(0, 0);
    ISSUE_B(0, 0);
    ISSUE_A_DMA(32, 1);
    ISSUE_B(32, 1);
  }

#pragma unroll
  for (int it = 0; it < 16; ++it) {
    if (it < 15) {
      if constexpr (F32A)
        asm volatile("s_waitcnt vmcnt(6) lgkmcnt(0)\n\ts_barrier" ::: "memory");
      else if constexpr (TM == 128)
        asm volatile("s_waitcnt vmcnt(4) lgkmcnt(0)\n\ts_barrier" ::: "memory");
      else
        asm volatile("s_waitcnt vmcnt(3) lgkmcnt(0)\n\ts_barrier" ::: "memory");
    } else {
      asm volatile("s_waitcnt vmcnt(0) lgkmcnt(0)\n\ts_barrier" ::: "memory");
    }
    if constexpr (F32A) {
      if (it < 15) CVT_WRITE_A((it + 1) % 3, (it + 1) & 1);  // FIRST
      if (it < 14) {
        LOAD_AFP((it + 2) * 32, it & 1);   // afp before same-stage B
        ISSUE_B((it + 2) * 32, (it + 2) % 3);
      }
    } else {
      if (it < 14) {
        ISSUE_A_DMA((it + 2) * 32, (it + 2) % 3);
        ISSUE_B((it + 2) * 32, (it + 2) % 3);
      }
    }
    const ushort* as = &smem[(it % 3) * A_STAGE];
    const ushort* bs = &smem[B_BASE + (it % 3) * 4096];
    bf16x8 af[4], br[NI];
#pragma unroll
    for (int mi = 0; mi < 4; ++mi)
      af[mi] = *(const bf16x8*)&as[(wm + mi * 16 + l15) * 32 + (qd ^ sw) * 8];
#pragma unroll
    for (int ni = 0; ni < NI; ++ni)
      br[ni] = *(const bf16x8*)&bs[(wn + ni * 16 + l15) * 32 + (qd ^ sw) * 8];
#pragma unroll
    for (int mi = 0; mi < 4; ++mi)
#pragma unroll
      for (int ni = 0; ni < NI; ++ni)
        acc[mi][ni] = __builtin_amdgcn_mfma_f32_16x16x32_bf16(
            af[mi], br[ni], acc[mi][ni], 0, 0, 0);
  }
#undef ISSUE_B
#undef ISSUE_A_DMA
#undef LOAD_AFP
#undef CVT_WRITE_A

  float bcol[NI];
#pragma unroll
  for (int ni = 0; ni < NI; ++ni) bcol[ni] = bias[col0 + wn + ni * 16 + l15];

  if (mode == 3) {  // fp32 direct stores
#pragma unroll
    for (int mi = 0; mi < 4; ++mi)
#pragma unroll
      for (int ni = 0; ni < NI; ++ni) {
        const int n_g = col0 + wn + ni * 16 + l15;
#pragma unroll
        for (int r = 0; r < 4; ++r) {
          const int token = row0 + wm + mi * 16 + qd * 4 + r;
          outp[(size_t)token * kD + n_g] = acc[mi][ni][r] + bcol[ni];
        }
      }
    return;
  }

  __syncthreads();  // reuse smem for epilogue transpose

  ushort* T = &smem[wave * 4608];
  if (mode <= 1) {  // [token_local][d_local]
#pragma unroll
    for (int mi = 0; mi < 4; ++mi)
#pragma unroll
      for (int ni = 0; ni < NI; ++ni)
#pragma unroll
        for (int r = 0; r < 4; ++r)
          T[(mi * 16 + qd * 4 + r) * 72 + ni * 16 + l15] =
              f2bf(acc[mi][ni][r] + bcol[ni]);
  } else {  // mode 2: [d_local][token_local]
#pragma unroll
    for (int mi = 0; mi < 4; ++mi)
#pragma unroll
      for (int ni = 0; ni < NI; ++ni)
#pragma unroll
        for (int r = 0; r < 4; ++r)
          T[(ni * 16 + l15) * 72 + mi * 16 + qd * 4 + r] =
              f2bf(acc[mi][ni][r] + bcol[ni]);
  }
  asm volatile("s_waitcnt lgkmcnt(0)" ::: "memory");

  const ushort* Trow = &smem[wave * 4608 + lane * 72];
  if (mode <= 1) {
    ushort* C = (mode == 0) ? Qp : Kp;
    ushort* dst = C + (size_t)(row0 + wm + lane) * kD + col0 + wn;
#pragma unroll
    for (int c = 0; c < 8; ++c)
      *(uint4*)(dst + c * 8) = *(const uint4*)(Trow + c * 8);
  } else {
    const int n_g = col0 + wn + lane;
    const int h = n_g >> 6, d = n_g & 63;
    const int t0 = row0 + wm;
    const int b = t0 >> 11, ss = t0 & (kS - 1);
    ushort* dst = VT + ((size_t)(b * kH + h) * 64 + d) * kS + ss;
#pragma unroll
    for (int c = 0; c < 8; ++c)
      *(uint4*)(dst + c * 8) = *(const uint4*)(Trow + c * 8);
  }
}

// ---------------------------------------------------------------------------
// MFMA banded attention. One wave per 64-query tile per (b,h). grid (32,32).
// ---------------------------------------------------------------------------
__global__ __launch_bounds__(64, 1) void attn_kernel(
    const ushort* __restrict__ Qp, const ushort* __restrict__ Kp,
    const ushort* __restrict__ VT, ushort* __restrict__ Ob) {
  __shared__ alignas(16) ushort Pl[64 * 104];

  const int lane = threadIdx.x, l15 = lane & 15, qd = lane >> 4;
  const int bh = blockIdx.y, b = bh >> 3, h = bh & 7;
  const int q0 = blockIdx.x * 64;
  const int colA = h * 64;

  bf16x8 qf[4][2], kf[6][2];
#pragma unroll
  for (int mi = 0; mi < 4; ++mi) {
    const size_t base =
        ((size_t)b * kS + q0 + mi * 16 + l15) * kD + colA + qd * 8;
#pragma unroll
    for (int kc = 0; kc < 2; ++kc)
      qf[mi][kc] = *(const bf16x8*)&Qp[base + kc * 32];
  }
#pragma unroll
  for (int ni = 0; ni < 6; ++ni) {
    int key = q0 - kBand + ni * 16 + l15;
    key = key < 0 ? 0 : (key > kS - 1 ? kS - 1 : key);
    const size_t base = ((size_t)b * kS + key) * kD + colA + qd * 8;
#pragma unroll
    for (int kc = 0; kc < 2; ++kc)
      kf[ni][kc] = *(const bf16x8*)&Kp[base + kc * 32];
  }

  f32x4 S[4][6];
#pragma unroll
  for (int mi = 0; mi < 4; ++mi)
#pragma unroll
    for (int ni = 0; ni < 6; ++ni) S[mi][ni] = (f32x4)(0.f);
#pragma unroll
  for (int mi = 0; mi < 4; ++mi)
#pragma unroll
    for (int ni = 0; ni < 6; ++ni)
#pragma unroll
      for (int kc = 0; kc < 2; ++kc)
        S[mi][ni] = __builtin_amdgcn_mfma_f32_16x16x32_bf16(
            qf[mi][kc], kf[ni][kc], S[mi][ni], 0, 0, 0);

#pragma unroll
  for (int mi = 0; mi < 4; ++mi)
#pragma unroll
    for (int ni = 0; ni < 6; ++ni)
#pragma unroll
      for (int r = 0; r < 4; ++r) {
        const int q_local = mi * 16 + qd * 4 + r;
        const int key_local = ni * 16 + l15;
        const int key = q0 - kBand + key_local;
        const int dlt = key_local - q_local;
        const bool ok = (dlt >= 0) && (dlt <= 32) && (key >= 0) && (key < kS);
        S[mi][ni][r] = ok ? S[mi][ni][r] * 0.125f : -3.0e38f;
      }

  float inv[4][4];
#pragma unroll
  for (int mi = 0; mi < 4; ++mi)
#pragma unroll
    for (int r = 0; r < 4; ++r) {
      float m = S[mi][0][r];
#pragma unroll
      for (int ni = 1; ni < 6; ++ni) m = fmaxf(m, S[mi][ni][r]);
      m = fmaxf(m, __shfl_xor(m, 1));
      m = fmaxf(m, __shfl_xor(m, 2));
      m = fmaxf(m, __shfl_xor(m, 4));
      m = fmaxf(m, __shfl_xor(m, 8));
      float s = 0.f;
#pragma unroll
      for (int ni = 0; ni < 6; ++ni) {
        const float e = __expf(S[mi][ni][r] - m);
        S[mi][ni][r] = e;
        s += e;
      }
      s += __shfl_xor(s, 1);
      s += __shfl_xor(s, 2);
      s += __shfl_xor(s, 4);
      s += __shfl_xor(s, 8);
      inv[mi][r] = 1.f / s;
    }

#pragma unroll
  for (int mi = 0; mi < 4; ++mi)
#pragma unroll
    for (int ni = 0; ni < 6; ++ni)
#pragma unroll
      for (int r = 0; r < 4; ++r)
        Pl[(mi * 16 + qd * 4 + r) * 104 + ni * 16 + l15] = f2bf(S[mi][ni][r]);
  __syncthreads();

  f32x4 O[4][4];
#pragma unroll
  for (int mi = 0; mi < 4; ++mi)
#pragma unroll
    for (int nt = 0; nt < 4; ++nt) O[mi][nt] = (f32x4)(0.f);

#pragma unroll
  for (int kc = 0; kc < 3; ++kc) {
    bf16x8 pf[4], vfr[4];
#pragma unroll
    for (int mi = 0; mi < 4; ++mi)
      pf[mi] = *(const bf16x8*)&Pl[(mi * 16 + l15) * 104 + kc * 32 + qd * 8];
    int kb0 = q0 - kBand + kc * 32 + qd * 8;
    kb0 = kb0 < 0 ? 0 : (kb0 > kS - 8 ? kS - 8 : kb0);
#pragma unroll
    for (int nt = 0; nt < 4; ++nt)
      vfr[nt] =
          *(const bf16x8*)&VT[((size_t)bh * 64 + nt * 16 + l15) * kS + kb0];
#pragma unroll
    for (int mi = 0; mi < 4; ++mi)
#pragma unroll
      for (int nt = 0; nt < 4; ++nt)
        O[mi][nt] = __builtin_amdgcn_mfma_f32_16x16x32_bf16(pf[mi], vfr[nt],
                                                            O[mi][nt], 0, 0, 0);
  }

#pragma unroll
  for (int mi = 0; mi < 4; ++mi)
#pragma unroll
    for (int nt = 0; nt < 4; ++nt)
#pragma unroll
      for (int r = 0; r < 4; ++r)
        Pl[(mi * 16 + qd * 4 + r) * 72 + nt * 16 + l15] =
            f2bf(O[mi][nt][r] * inv[mi][r]);
  asm volatile("s_waitcnt lgkmcnt(0)" ::: "memory");

  ushort* dst = Ob + ((size_t)b * kS + q0 + lane) * kD + colA;
  const ushort* Trow = &Pl[lane * 72];
#pragma unroll
  for (int c = 0; c < 8; ++c)
    *(uint4*)(dst + c * 8) = *(const uint4*)(Trow + c * 8);
}

extern "C" void kernel_launch(void* const* d_in, const int* in_sizes, int n_in,
                              void* d_out, int out_size, void* d_ws,
                              size_t ws_size, hipStream_t stream) {
  const float* q = (const float*)d_in[0];
  const float* k = (const float*)d_in[1];
  const float* v = (const float*)d_in[2];
  const float* wq = (const float*)d_in[3];
  const float* bq = (const float*)d_in[4];
  const float* wk = (const float*)d_in[5];
  const float* bk = (const float*)d_in[6];
  const float* wv = (const float*)d_in[7];
  const float* bv = (const float*)d_in[8];
  const float* wo = (const float*)d_in[9];
  const float* bo = (const float*)d_in[10];
  float* out = (float*)d_out;

  // ws (~34 MB): Qp | Kp | VT | Ob | WT
  const size_t n1 = (size_t)kNT * kD;  // 8 MB each (bf16)
  ushort* Qp = (ushort*)d_ws;
  ushort* Kp = Qp + n1;
  ushort* VT = Kp + n1;
  ushort* Ob = VT + n1;
  ushort* WT = Ob + n1;

  prep_w_kernel<<<dim3(256), 256, 0, stream>>>(wq, wk, wv, wo, WT);
  gemm_kernel<128, true><<<dim3(256, 1, 3), 256, 0, stream>>>(  // modes 0,1,2
      q, k, v, Ob, WT, bq, bk, bv, bo, Qp, Kp, VT, out, 0);
  attn_kernel<<<dim3(kS / 64, 32), 64, 0, stream>>>(Qp, Kp, VT, Ob);
  gemm_kernel<64, false><<<dim3(512, 1, 1), 256, 0, stream>>>(  // mode 3
      q, k, v, Ob, WT, bq, bk, bv, bo, Qp, Kp, VT, out, 3);
}